// Round 1
// baseline (698.119 us; speedup 1.0000x reference)
//
#include <hip/hip_runtime.h>
#include <stdint.h>

#define BATCH 4
#define SEQL  16384
#define DIM   64
#define NST   16
#define TOK   (BATCH*SEQL)        /* 65536 tokens */
#define EL    (TOK*DIM)           /* 4194304 elems per [B,L,D] array */
#define NCH   256                 /* chunks per (b,dir) */
#define CHL   64                  /* chunk length; NCH*CHL == SEQL */

__device__ __forceinline__ float nan2num(float x, float nv, float pv, float mv){
  if (__builtin_isnan(x)) return nv;
  if (__builtin_isinf(x)) return x > 0.f ? pv : mv;
  return x;
}
__device__ __forceinline__ float wsum64(float v){
  #pragma unroll
  for (int off = 32; off > 0; off >>= 1) v += __shfl_xor(v, off, 64);
  return v;
}
__device__ __forceinline__ float siluf(float x){ return x / (1.f + __expf(-x)); }
__device__ __forceinline__ float b2f(unsigned short s){
  union { unsigned u; float f; } v; v.u = ((unsigned)s) << 16; return v.f;
}
__device__ __forceinline__ unsigned short f2b(float f){
  union { float f; unsigned u; } v; v.f = f;
  unsigned r = v.u + 0x7fffu + ((v.u >> 16) & 1u);   // RNE
  return (unsigned short)(r >> 16);
}

struct US2 { unsigned short x, y; };

// ---------------------------------------------------------------- K1: pre
// wave-per-token: nan_to_num, LN(x0), LN(x1), gate w, in_proj, in_proj_e
__global__ __launch_bounds__(1024) void k1_pre(
    const float* __restrict__ in0, const float* __restrict__ in1,
    const float* __restrict__ n0w, const float* __restrict__ n0b,
    const float* __restrict__ n1w, const float* __restrict__ n1b,
    const float* __restrict__ cww, const float* __restrict__ cwb,
    const float* __restrict__ cwnw, const float* __restrict__ cwnb,
    const float* __restrict__ ipw, const float* __restrict__ ipew,
    float* __restrict__ x0n, float* __restrict__ wg,
    float* __restrict__ xa,  float* __restrict__ z,
    float* __restrict__ xe,  float* __restrict__ ze)
{
  // bf16 weight staging (48 KB LDS): cw2[d*64+j]={W[j][d],W[j][64+d]},
  // ip2[d*64+j]={ipw[j][d],ipw[j+64][d]}, ipe2 likewise.
  __shared__ US2 cw2[4096], ip2[4096], ipe2[4096];
  int tid = threadIdx.x;
  for (int idx = tid; idx < 4096; idx += 1024){
    int d = idx >> 6, j = idx & 63;
    cw2[idx]  = US2{ f2b(cww[j*128 + d]),  f2b(cww[j*128 + 64 + d]) };
    ip2[idx]  = US2{ f2b(ipw[j*64 + d]),   f2b(ipw[(j+64)*64 + d]) };
    ipe2[idx] = US2{ f2b(ipew[j*64 + d]),  f2b(ipew[(j+64)*64 + d]) };
  }
  __syncthreads();
  int lane = tid & 63, wv = tid >> 6;
  float gw0 = n0w[lane], gb0 = n0b[lane], gw1 = n1w[lane], gb1 = n1b[lane];
  float gcb = cwb[lane], gcnw = cwnw[lane], gcnb = cwnb[lane];
  for (int t = blockIdx.x*16 + wv; t < TOK; t += gridDim.x*16){
    int off = t*64 + lane;
    float v0 = nan2num(in0[off], 0.f, 1.f, -1.f);
    float v1 = nan2num(in1[off], 0.f, 1.f, -1.f);
    float m0 = wsum64(v0)*(1.f/64.f);
    float q0 = wsum64(v0*v0)*(1.f/64.f) - m0*m0;
    float x0 = nan2num((v0-m0)*rsqrtf(q0+1e-5f)*gw0 + gb0, 0.f, 1.f, -1.f);
    float m1 = wsum64(v1)*(1.f/64.f);
    float q1 = wsum64(v1*v1)*(1.f/64.f) - m1*m1;
    float x1 = nan2num((v1-m1)*rsqrtf(q1+1e-5f)*gw1 + gb1, 0.f, 1.f, -1.f);

    float accw = gcb, accx = 0.f, accz = 0.f, accxe = 0.f, accze = 0.f;
    #pragma unroll 8
    for (int d = 0; d < 64; ++d){
      float a0 = __shfl(x0, d, 64);
      float a1 = __shfl(x1, d, 64);
      US2 cw = cw2[d*64 + lane];
      accw += b2f(cw.x)*a0 + b2f(cw.y)*a1;
      US2 ip = ip2[d*64 + lane];
      accx += b2f(ip.x)*a0; accz += b2f(ip.y)*a0;
      US2 ie = ipe2[d*64 + lane];
      accxe += b2f(ie.x)*a1; accze += b2f(ie.y)*a1;
    }
    float mw = wsum64(accw)*(1.f/64.f);
    float qw = wsum64(accw*accw)*(1.f/64.f) - mw*mw;
    float wn = (accw-mw)*rsqrtf(qw+1e-5f)*gcnw + gcnb;
    wn = nan2num(wn, 0.5f, 1.f, 0.f);
    wn = 1.f/(1.f + __expf(-wn));
    wn = fminf(fmaxf(wn, 0.01f), 0.99f);

    x0n[off] = x0; wg[off] = wn;
    xa[off] = accx; z[off] = accz; xe[off] = accxe; ze[off] = accze;
  }
}

// ---------------------------------------------------------------- K2: conv
// forward: causal conv on xa; reverse: anti-causal conv on xe (flip folded in)
__global__ __launch_bounds__(256) void k2_conv(
    const float* __restrict__ xa, const float* __restrict__ xe,
    const float* __restrict__ cwf, const float* __restrict__ cbf,
    const float* __restrict__ cwr, const float* __restrict__ cbr,
    float* __restrict__ uf, float* __restrict__ ur)
{
  int g = blockIdx.x*256 + threadIdx.x;
  int d = g & 63, t = g >> 6, l = t & (SEQL-1);
  float4 wf = ((const float4*)cwf)[d];
  float4 wr = ((const float4*)cwr)[d];
  float a = cbf[d] + wf.w * xa[g];
  if (l >= 1) a += wf.z * xa[g - 64];
  if (l >= 2) a += wf.y * xa[g - 128];
  if (l >= 3) a += wf.x * xa[g - 192];
  uf[g] = siluf(a);
  float r = cbr[d] + wr.w * xe[g];
  if (l + 1 < SEQL) r += wr.z * xe[g + 64];
  if (l + 2 < SEQL) r += wr.y * xe[g + 128];
  if (l + 3 < SEQL) r += wr.x * xe[g + 192];
  ur[g] = siluf(r);
}

// ---------------------------------------------------------------- K3: x-proj
#define XSTR 40
__global__ __launch_bounds__(1024) void k3_xproj(
    const float* __restrict__ uf, const float* __restrict__ ur,
    const float* __restrict__ xpwf, const float* __restrict__ xpwr,
    const float* __restrict__ dtwf, const float* __restrict__ dtbf,
    const float* __restrict__ dtwr, const float* __restrict__ dtbr,
    float* __restrict__ dtf, float* __restrict__ dtr,
    float* __restrict__ Bf, float* __restrict__ Cf,
    float* __restrict__ Br, float* __restrict__ Cr)
{
  __shared__ float XT[2*64*XSTR + 64];
  int tid = threadIdx.x;
  for (int idx = tid; idx < 2*64*XSTR + 64; idx += 1024) XT[idx] = 0.f;
  __syncthreads();
  for (int idx = tid; idx < 2*64*36; idx += 1024){
    int dir = idx >= 64*36;
    int r = idx - dir*64*36;
    int d = r/36, j = r - d*36;
    XT[dir*64*XSTR + d*XSTR + j] = (dir ? xpwr : xpwf)[j*64 + d];
  }
  __syncthreads();
  int lane = tid & 63, wv = tid >> 6;
  float4 wdt_f = ((const float4*)dtwf)[lane];
  float4 wdt_r = ((const float4*)dtwr)[lane];
  float bdt_f = dtbf[lane], bdt_r = dtbr[lane];
  for (int t = blockIdx.x*16 + wv; t < TOK; t += gridDim.x*16){
    #pragma unroll
    for (int dir = 0; dir < 2; ++dir){
      const float* u = dir ? ur : uf;
      const float* XTd = XT + dir*64*XSTR;
      float uv = u[t*64 + lane];
      float acc = 0.f;
      #pragma unroll 8
      for (int d = 0; d < 64; ++d){
        float a = __shfl(uv, d, 64);
        acc += XTd[d*XSTR + lane] * a;   // lanes >=36 compute garbage, unused
      }
      float d0 = __shfl(acc, 0, 64), d1 = __shfl(acc, 1, 64);
      float d2 = __shfl(acc, 2, 64), d3 = __shfl(acc, 3, 64);
      float4 wd = dir ? wdt_r : wdt_f;
      float dtv = wd.x*d0 + wd.y*d1 + wd.z*d2 + wd.w*d3 + (dir ? bdt_r : bdt_f);
      dtv = dtv > 20.f ? dtv : log1pf(__expf(dtv));   // softplus
      (dir ? dtr : dtf)[t*64 + lane] = dtv;
      if (lane >= 4  && lane < 20) (dir ? Br : Bf)[t*16 + lane - 4]  = acc;
      if (lane >= 20 && lane < 36) (dir ? Cr : Cf)[t*16 + lane - 20] = acc;
    }
  }
}

// ---------------------------------------------------------------- K4a: chunk compose
// thread per (b,dir,d,chunk): P[n] = prod a, S[n] = composed b over the chunk
__global__ __launch_bounds__(256) void k4a_scanA(
    const float* __restrict__ dtf, const float* __restrict__ dtr,
    const float* __restrict__ uf,  const float* __restrict__ ur,
    const float* __restrict__ Bf,  const float* __restrict__ Br,
    const float* __restrict__ Alf, const float* __restrict__ Alr,
    float* __restrict__ P, float* __restrict__ S)
{
  int g = blockIdx.x*256 + threadIdx.x;     // 131072 threads
  int d = g & 63, c = (g >> 6) & (NCH-1), dir = (g >> 14) & 1, b = g >> 15;
  const float* dt = dir ? dtr : dtf;
  const float* u  = dir ? ur  : uf;
  const float* Bm = dir ? Br  : Bf;
  const float* Al = dir ? Alr : Alf;
  float A[16], Pp[16], Ss[16];
  #pragma unroll
  for (int n = 0; n < 16; n++){ A[n] = -__expf(Al[d*16+n]); Pp[n] = 1.f; Ss[n] = 0.f; }
  int base = b*SEQL;
  for (int i = 0; i < CHL; i++){
    int s = c*CHL + i;
    int l = dir ? (SEQL-1-s) : s;
    int off = (base + l)*64 + d;
    float dtv = dt[off];
    float du  = dtv * u[off];
    const float4* B4 = (const float4*)(Bm + (size_t)(base + l)*16);
    float4 b0 = B4[0], b1 = B4[1], b2 = B4[2], b3 = B4[3];
    float bb[16] = {b0.x,b0.y,b0.z,b0.w, b1.x,b1.y,b1.z,b1.w,
                    b2.x,b2.y,b2.z,b2.w, b3.x,b3.y,b3.z,b3.w};
    #pragma unroll
    for (int n = 0; n < 16; n++){
      float a = __expf(dtv*A[n]);
      Pp[n] *= a;
      Ss[n] = fmaf(a, Ss[n], du*bb[n]);
    }
  }
  float4* P4 = (float4*)P; float4* S4 = (float4*)S;
  #pragma unroll
  for (int k = 0; k < 4; k++){
    P4[g*4+k] = make_float4(Pp[4*k], Pp[4*k+1], Pp[4*k+2], Pp[4*k+3]);
    S4[g*4+k] = make_float4(Ss[4*k], Ss[4*k+1], Ss[4*k+2], Ss[4*k+3]);
  }
}

// ---------------------------------------------------------------- K4b: carry scan
// thread per (b,dir,d,n); in place: P[c] becomes the prefix state before chunk c
__global__ __launch_bounds__(256) void k4b_carry(float* __restrict__ P,
                                                 const float* __restrict__ S)
{
  int g = blockIdx.x*256 + threadIdx.x;     // 8192 threads
  int n = g & 15, d = (g >> 4) & 63, bd = g >> 10;
  float H = 0.f;
  for (int c = 0; c < NCH; c++){
    int idx = ((bd*NCH + c)*64 + d)*16 + n;
    float p = P[idx], s = S[idx];
    P[idx] = H;
    H = fmaf(p, H, s);
  }
}

// ---------------------------------------------------------------- K4c: scan pass B
__global__ __launch_bounds__(256) void k4c_scanB(
    const float* __restrict__ dtf, const float* __restrict__ dtr,
    const float* __restrict__ uf,  const float* __restrict__ ur,
    const float* __restrict__ Bf,  const float* __restrict__ Br,
    const float* __restrict__ Cf,  const float* __restrict__ Cr,
    const float* __restrict__ Alf, const float* __restrict__ Alr,
    const float* __restrict__ Dvf, const float* __restrict__ Dvr,
    const float* __restrict__ Hpre, float* __restrict__ yf, float* __restrict__ yr)
{
  int g = blockIdx.x*256 + threadIdx.x;
  int d = g & 63, c = (g >> 6) & (NCH-1), dir = (g >> 14) & 1, b = g >> 15;
  const float* dt = dir ? dtr : dtf;
  const float* u  = dir ? ur  : uf;
  const float* Bm = dir ? Br  : Bf;
  const float* Cm = dir ? Cr  : Cf;
  const float* Al = dir ? Alr : Alf;
  float Dd = (dir ? Dvr : Dvf)[d];
  float* y = dir ? yr : yf;
  float A[16], h[16];
  const float4* H4 = (const float4*)Hpre;
  #pragma unroll
  for (int k = 0; k < 4; k++){
    float4 hv = H4[g*4+k];
    h[4*k] = hv.x; h[4*k+1] = hv.y; h[4*k+2] = hv.z; h[4*k+3] = hv.w;
  }
  #pragma unroll
  for (int n = 0; n < 16; n++) A[n] = -__expf(Al[d*16+n]);
  int base = b*SEQL;
  for (int i = 0; i < CHL; i++){
    int s = c*CHL + i;
    int l = dir ? (SEQL-1-s) : s;
    int off = (base + l)*64 + d;
    float dtv = dt[off];
    float uv  = u[off];
    float du  = dtv*uv;
    const float4* B4 = (const float4*)(Bm + (size_t)(base + l)*16);
    const float4* C4 = (const float4*)(Cm + (size_t)(base + l)*16);
    float4 b0 = B4[0], b1 = B4[1], b2 = B4[2], b3 = B4[3];
    float4 c0 = C4[0], c1 = C4[1], c2 = C4[2], c3 = C4[3];
    float bb[16] = {b0.x,b0.y,b0.z,b0.w, b1.x,b1.y,b1.z,b1.w,
                    b2.x,b2.y,b2.z,b2.w, b3.x,b3.y,b3.z,b3.w};
    float cc[16] = {c0.x,c0.y,c0.z,c0.w, c1.x,c1.y,c1.z,c1.w,
                    c2.x,c2.y,c2.z,c2.w, c3.x,c3.y,c3.z,c3.w};
    float yv = uv*Dd;
    #pragma unroll
    for (int n = 0; n < 16; n++){
      float a = __expf(dtv*A[n]);
      h[n] = fmaf(a, h[n], du*bb[n]);
      yv = fmaf(h[n], cc[n], yv);
    }
    y[off] = yv;
  }
}

// ---------------------------------------------------------------- K5: epilogue
__global__ __launch_bounds__(1024) void k5_post(
    const float* __restrict__ yf, const float* __restrict__ yr,
    const float* __restrict__ z,  const float* __restrict__ ze,
    const float* __restrict__ wg, const float* __restrict__ x0n,
    const float* __restrict__ in0,
    const float* __restrict__ mnw, const float* __restrict__ opw,
    const float* __restrict__ pnw, const float* __restrict__ pnb,
    float* __restrict__ out)
{
  __shared__ float opT[4096];   // opT[d*64+j] = opw[j*64+d]
  int tid = threadIdx.x;
  for (int idx = tid; idx < 4096; idx += 1024){
    int d = idx >> 6, j = idx & 63;
    opT[idx] = opw[j*64 + d];
  }
  __syncthreads();
  int lane = tid & 63, wv = tid >> 6;
  float gmn = mnw[lane], gpw = pnw[lane], gpb = pnb[lane];
  for (int t = blockIdx.x*16 + wv; t < TOK; t += gridDim.x*16){
    int off = t*64 + lane;
    float vy = 0.5f*( yf[off]*siluf(z[off]) + yr[off]*siluf(ze[off]) );
    float ms = wsum64(vy*vy)*(1.f/64.f);
    float yn = vy * rsqrtf(ms + 1e-5f) * gmn;
    float acc = 0.f;
    #pragma unroll 8
    for (int d = 0; d < 64; ++d){
      float a = __shfl(yn, d, 64);
      acc += opT[d*64 + lane]*a;
    }
    float m = wsum64(acc)*(1.f/64.f);
    float q = wsum64(acc*acc)*(1.f/64.f) - m*m;
    float o = (acc - m)*rsqrtf(q + 1e-5f)*gpw + gpb;
    o = nan2num(o, 0.f, 1.f, -1.f);
    float w = wg[off];
    float skip = nan2num(in0[off], 0.f, 1.f, -1.f);
    out[off] = fmaf(o, w, fmaf(x0n[off], 1.f - w, skip));
  }
}

// ---------------------------------------------------------------- launcher
extern "C" void kernel_launch(void* const* d_in, const int* in_sizes, int n_in,
                              void* d_out, int out_size, void* d_ws, size_t ws_size,
                              hipStream_t stream)
{
  (void)in_sizes; (void)n_in; (void)out_size; (void)ws_size;
  const float* in0  = (const float*)d_in[0];
  const float* in1  = (const float*)d_in[1];
  const float* n0w  = (const float*)d_in[2];
  const float* n0b  = (const float*)d_in[3];
  const float* n1w  = (const float*)d_in[4];
  const float* n1b  = (const float*)d_in[5];
  const float* cww  = (const float*)d_in[6];
  const float* cwb  = (const float*)d_in[7];
  const float* cwnw = (const float*)d_in[8];
  const float* cwnb = (const float*)d_in[9];
  const float* ipw  = (const float*)d_in[10];
  const float* ipew = (const float*)d_in[11];
  const float* cwf  = (const float*)d_in[12];
  const float* cbf  = (const float*)d_in[13];
  const float* xpwf = (const float*)d_in[14];
  const float* dtwf = (const float*)d_in[15];
  const float* dtbf = (const float*)d_in[16];
  const float* Alf  = (const float*)d_in[17];
  const float* Dvf  = (const float*)d_in[18];
  const float* cwr  = (const float*)d_in[19];
  const float* cbr  = (const float*)d_in[20];
  const float* xpwr = (const float*)d_in[21];
  const float* dtwr = (const float*)d_in[22];
  const float* dtbr = (const float*)d_in[23];
  const float* Alr  = (const float*)d_in[24];
  const float* Dvr  = (const float*)d_in[25];
  const float* mnw  = (const float*)d_in[26];
  const float* opw  = (const float*)d_in[27];
  const float* pnw  = (const float*)d_in[28];
  const float* pnb  = (const float*)d_in[29];

  float* ws  = (float*)d_ws;
  float* x0n = ws;
  float* wg  = ws + (size_t)1*EL;
  float* z   = ws + (size_t)2*EL;
  float* ze  = ws + (size_t)3*EL;
  float* xa  = ws + (size_t)4*EL;   // later reused as yf
  float* xe  = ws + (size_t)5*EL;   // later reused as yr
  float* uf  = ws + (size_t)6*EL;
  float* ur  = ws + (size_t)7*EL;
  float* dtf = ws + (size_t)8*EL;
  float* dtr = ws + (size_t)9*EL;
  float* Bf  = ws + (size_t)10*EL;            // each B/C: TOK*16 = EL/4
  float* Cf  = Bf + (size_t)TOK*16;
  float* Br  = Cf + (size_t)TOK*16;
  float* Cr  = Br + (size_t)TOK*16;
  float* P   = ws + (size_t)11*EL;            // NCH scan carries: EL/2 each
  float* S   = P + (size_t)BATCH*2*DIM*NCH*NST/1; // offset in floats below
  S = P + (size_t)2*TOK*16;                   // 131072*16 = EL/2
  float* yfp = xa;
  float* yrp = xe;

  k1_pre<<<256, 1024, 0, stream>>>(in0, in1, n0w, n0b, n1w, n1b, cww, cwb,
                                   cwnw, cwnb, ipw, ipew,
                                   x0n, wg, xa, z, xe, ze);
  k2_conv<<<EL/256, 256, 0, stream>>>(xa, xe, cwf, cbf, cwr, cbr, uf, ur);
  k3_xproj<<<256, 1024, 0, stream>>>(uf, ur, xpwf, xpwr, dtwf, dtbf, dtwr, dtbr,
                                     dtf, dtr, Bf, Cf, Br, Cr);
  k4a_scanA<<<512, 256, 0, stream>>>(dtf, dtr, uf, ur, Bf, Br, Alf, Alr, P, S);
  k4b_carry<<<32, 256, 0, stream>>>(P, S);
  k4c_scanB<<<512, 256, 0, stream>>>(dtf, dtr, uf, ur, Bf, Br, Cf, Cr,
                                     Alf, Alr, Dvf, Dvr, P, yfp, yrp);
  k5_post<<<256, 1024, 0, stream>>>(yfp, yrp, z, ze, wg, x0n, in0,
                                    mnw, opw, pnw, pnb, (float*)d_out);
}

// Round 2
// 426.079 us; speedup vs baseline: 1.6385x; 1.6385x over previous
//
#include <hip/hip_runtime.h>
#include <stdint.h>

#define BATCH 4
#define SEQL  16384
#define DIM   64
#define NST   16
#define TOK   (BATCH*SEQL)        /* 65536 tokens */
#define EL    ((size_t)TOK*DIM)   /* 4194304 elems per [B,L,D] array */
#define NCH   256                 /* chunks per (b,dir) */
#define CHL   64                  /* chunk length; NCH*CHL == SEQL */

typedef __attribute__((ext_vector_type(8))) short short8;
typedef __attribute__((ext_vector_type(4))) float f32x4;

__device__ __forceinline__ float nan2num(float x, float nv, float pv, float mv){
  if (__builtin_isnan(x)) return nv;
  if (__builtin_isinf(x)) return x > 0.f ? pv : mv;
  return x;
}
__device__ __forceinline__ float wsum64(float v){
  #pragma unroll
  for (int off = 32; off > 0; off >>= 1) v += __shfl_xor(v, off, 64);
  return v;
}
__device__ __forceinline__ float siluf(float x){ return x / (1.f + __expf(-x)); }
__device__ __forceinline__ float b2f(unsigned short s){
  union { unsigned u; float f; } v; v.u = ((unsigned)s) << 16; return v.f;
}
__device__ __forceinline__ unsigned short f2b(float f){
  union { float f; unsigned u; } v; v.f = f;
  unsigned r = v.u + 0x7fffu + ((v.u >> 16) & 1u);   // RNE
  return (unsigned short)(r >> 16);
}

// ================================================================ P1: LN
// wave-per-token: nan_to_num + LayerNorm for both inputs; emit fp32 x0n and
// bf16 copies of x0,x1 for the MFMA GEMMs.
__global__ __launch_bounds__(256) void p1_ln(
    const float* __restrict__ in0, const float* __restrict__ in1,
    const float* __restrict__ n0w, const float* __restrict__ n0b,
    const float* __restrict__ n1w, const float* __restrict__ n1b,
    float* __restrict__ x0n,
    unsigned short* __restrict__ x0b, unsigned short* __restrict__ x1b)
{
  int lane = threadIdx.x & 63, wv = threadIdx.x >> 6;
  float gw0 = n0w[lane], gb0 = n0b[lane], gw1 = n1w[lane], gb1 = n1b[lane];
  for (int t = blockIdx.x*4 + wv; t < TOK; t += gridDim.x*4){
    size_t off = (size_t)t*64 + lane;
    float v0 = nan2num(in0[off], 0.f, 1.f, -1.f);
    float v1 = nan2num(in1[off], 0.f, 1.f, -1.f);
    float m0 = wsum64(v0)*(1.f/64.f);
    float q0 = wsum64(v0*v0)*(1.f/64.f) - m0*m0;
    float x0 = nan2num((v0-m0)*rsqrtf(q0+1e-5f)*gw0 + gb0, 0.f, 1.f, -1.f);
    float m1 = wsum64(v1)*(1.f/64.f);
    float q1 = wsum64(v1*v1)*(1.f/64.f) - m1*m1;
    float x1 = nan2num((v1-m1)*rsqrtf(q1+1e-5f)*gw1 + gb1, 0.f, 1.f, -1.f);
    x0n[off] = x0;
    x0b[off] = f2b(x0);
    x1b[off] = f2b(x1);
  }
}

// ================================================================ G1: proj GEMM
// [64 tok] x [64 K] @ [64 K x 192 out] per block. out-tiles: 0-3 -> w partial,
// 4-7 -> x (conv input, fp32), 8-11 -> z (bf16).
__global__ __launch_bounds__(256) void g1_proj(
    const unsigned short* __restrict__ xb,   // [T*64] bf16
    const float* __restrict__ cw_src,        // cww + s*64, row stride 128
    const float* __restrict__ ip_src,        // [128*64]
    float* __restrict__ outw,                // [T*64] fp32 w partial
    float* __restrict__ outx,                // [T*64] fp32
    unsigned short* __restrict__ outz)       // [T*64] bf16
{
  __shared__ __align__(16) short Wl[192*72];
  __shared__ __align__(16) short Al[64*72];
  int tid = threadIdx.x;
  int t0 = blockIdx.x * 64;
  for (int sseg = tid; sseg < 192*8; sseg += 256){
    int row = sseg >> 3, sg = sseg & 7;
    const float* src = (row < 64) ? (cw_src + (size_t)row*128 + sg*8)
                                  : (ip_src + (size_t)(row-64)*64 + sg*8);
    float4 f0 = ((const float4*)src)[0];
    float4 f1 = ((const float4*)src)[1];
    short8 v;
    v[0]=(short)f2b(f0.x); v[1]=(short)f2b(f0.y); v[2]=(short)f2b(f0.z); v[3]=(short)f2b(f0.w);
    v[4]=(short)f2b(f1.x); v[5]=(short)f2b(f1.y); v[6]=(short)f2b(f1.z); v[7]=(short)f2b(f1.w);
    *(short8*)&Wl[row*72 + sg*8] = v;
  }
  for (int sseg = tid; sseg < 64*8; sseg += 256){
    int row = sseg >> 3, sg = sseg & 7;
    short8 v = *(const short8*)(xb + (size_t)(t0+row)*64 + sg*8);
    *(short8*)&Al[row*72 + sg*8] = v;
  }
  __syncthreads();
  int lane = tid & 63, wv = tid >> 6;
  int n = lane & 15, q = lane >> 4;
  short8 a0 = *(const short8*)&Al[(wv*16 + n)*72 + q*8];
  short8 a1 = *(const short8*)&Al[(wv*16 + n)*72 + 32 + q*8];
  f32x4 acc[12];
  #pragma unroll
  for (int o = 0; o < 12; ++o){
    short8 b0 = *(const short8*)&Wl[(o*16 + n)*72 + q*8];
    short8 b1 = *(const short8*)&Wl[(o*16 + n)*72 + 32 + q*8];
    f32x4 c = {0.f, 0.f, 0.f, 0.f};
    c = __builtin_amdgcn_mfma_f32_16x16x32_bf16(a0, b0, c, 0, 0, 0);
    c = __builtin_amdgcn_mfma_f32_16x16x32_bf16(a1, b1, c, 0, 0, 0);
    acc[o] = c;
  }
  #pragma unroll
  for (int o = 0; o < 12; ++o){
    #pragma unroll
    for (int r = 0; r < 4; ++r){
      size_t tok = (size_t)t0 + wv*16 + q*4 + r;
      float v = acc[o][r];
      if (o < 4)       outw[tok*64 + o*16 + n] = v;
      else if (o < 8)  outx[tok*64 + (o-4)*16 + n] = v;
      else             outz[tok*64 + (o-8)*16 + n] = f2b(v);
    }
  }
}

// ================================================================ K_wln: gate
__global__ __launch_bounds__(256) void k_wln(
    const float* __restrict__ w0, const float* __restrict__ w1,
    const float* __restrict__ cwb,
    const float* __restrict__ cwnw, const float* __restrict__ cwnb,
    float* __restrict__ wg)
{
  int lane = threadIdx.x & 63, wv = threadIdx.x >> 6;
  float bb = cwb[lane], gw = cwnw[lane], gb = cwnb[lane];
  for (int t = blockIdx.x*4 + wv; t < TOK; t += gridDim.x*4){
    size_t off = (size_t)t*64 + lane;
    float v = w0[off] + w1[off] + bb;
    float m = wsum64(v)*(1.f/64.f);
    float qv = wsum64(v*v)*(1.f/64.f) - m*m;
    float wn = (v-m)*rsqrtf(qv+1e-5f)*gw + gb;
    wn = nan2num(wn, 0.5f, 1.f, 0.f);
    wn = 1.f/(1.f + __expf(-wn));
    wg[off] = fminf(fmaxf(wn, 0.01f), 0.99f);
  }
}

// ================================================================ G2: conv + xproj
// fuses depthwise conv (fwd causal / rev anti-causal) + silu, writes uf/ur fp32,
// stages bf16 u into LDS, GEMM [64x64]@[64x48] per stream, dt via shfl+softplus.
// W LDS rows: 0-15 = B (src rows 4-19), 16-31 = C (src 20-35), 32-35 = dt (src 0-3).
__global__ __launch_bounds__(256) void g2_convproj(
    const float* __restrict__ xa, const float* __restrict__ xe,
    const float* __restrict__ cwf, const float* __restrict__ cbf,
    const float* __restrict__ cwr, const float* __restrict__ cbr,
    const float* __restrict__ xpwf, const float* __restrict__ xpwr,
    const float* __restrict__ dtwf, const float* __restrict__ dtbf,
    const float* __restrict__ dtwr, const float* __restrict__ dtbr,
    float* __restrict__ uf, float* __restrict__ ur,
    float* __restrict__ dtf, float* __restrict__ dtr,
    float* __restrict__ Bf, float* __restrict__ Cf,
    float* __restrict__ Br, float* __restrict__ Cr)
{
  __shared__ __align__(16) short Wl[2*48*72];
  __shared__ __align__(16) short Al[2*64*72];
  int tid = threadIdx.x;
  int b = blockIdx.x >> 8, l0 = (blockIdx.x & 255) * 64;
  size_t base = (size_t)b * SEQL;
  // stage weights
  for (int sseg = tid; sseg < 2*48*8; sseg += 256){
    int s = sseg >= 48*8;
    int rs = sseg - s*48*8;
    int row = rs >> 3, sg = rs & 7;
    const float* xp = s ? xpwr : xpwf;
    short8 v = {0,0,0,0,0,0,0,0};
    int srcrow = (row < 16) ? (4+row) : (row < 32) ? (4+row) /*20+(row-16)*/ : (row < 36) ? (row-32) : -1;
    if (srcrow >= 0){
      const float* src = xp + (size_t)srcrow*64 + sg*8;
      float4 f0 = ((const float4*)src)[0];
      float4 f1 = ((const float4*)src)[1];
      v[0]=(short)f2b(f0.x); v[1]=(short)f2b(f0.y); v[2]=(short)f2b(f0.z); v[3]=(short)f2b(f0.w);
      v[4]=(short)f2b(f1.x); v[5]=(short)f2b(f1.y); v[6]=(short)f2b(f1.z); v[7]=(short)f2b(f1.w);
    }
    *(short8*)&Wl[(s*48+row)*72 + sg*8] = v;
  }
  // conv + silu + stage A + write u
  for (int e = tid; e < 4096; e += 256){
    int l = e >> 6, d = e & 63;
    int gl = l0 + l;
    size_t g = (base + gl)*64 + d;
    float4 wf4 = ((const float4*)cwf)[d];
    float a = cbf[d] + wf4.w * xa[g];
    if (gl >= 1) a += wf4.z * xa[g - 64];
    if (gl >= 2) a += wf4.y * xa[g - 128];
    if (gl >= 3) a += wf4.x * xa[g - 192];
    a = siluf(a);
    uf[g] = a;
    Al[l*72 + d] = (short)f2b(a);
    float4 wr4 = ((const float4*)cwr)[d];
    float r = cbr[d] + wr4.w * xe[g];
    if (gl + 1 < SEQL) r += wr4.z * xe[g + 64];
    if (gl + 2 < SEQL) r += wr4.y * xe[g + 128];
    if (gl + 3 < SEQL) r += wr4.x * xe[g + 192];
    r = siluf(r);
    ur[g] = r;
    Al[(64 + l)*72 + d] = (short)f2b(r);
  }
  __syncthreads();
  int lane = tid & 63, wv = tid >> 6;
  int n = lane & 15, q = lane >> 4;
  #pragma unroll
  for (int s = 0; s < 2; ++s){
    const short* As = &Al[s*64*72];
    const short* Ws = &Wl[s*48*72];
    short8 a0 = *(const short8*)&As[(wv*16 + n)*72 + q*8];
    short8 a1 = *(const short8*)&As[(wv*16 + n)*72 + 32 + q*8];
    f32x4 acc[3];
    #pragma unroll
    for (int o = 0; o < 3; ++o){
      short8 b0 = *(const short8*)&Ws[(o*16 + n)*72 + q*8];
      short8 b1 = *(const short8*)&Ws[(o*16 + n)*72 + 32 + q*8];
      f32x4 c = {0.f, 0.f, 0.f, 0.f};
      c = __builtin_amdgcn_mfma_f32_16x16x32_bf16(a0, b0, c, 0, 0, 0);
      c = __builtin_amdgcn_mfma_f32_16x16x32_bf16(a1, b1, c, 0, 0, 0);
      acc[o] = c;
    }
    float* Bo = s ? Br : Bf;
    float* Co = s ? Cr : Cf;
    #pragma unroll
    for (int r = 0; r < 4; ++r){
      size_t tok = base + l0 + wv*16 + q*4 + r;
      Bo[tok*16 + n] = acc[0][r];
      Co[tok*16 + n] = acc[1][r];
    }
    // dt: tile 2 cols 0-3 hold dlt[token][0..3]; broadcast via shfl
    const float* dtw = s ? dtwr : dtwf;
    float4 wd = ((const float4*)dtw)[lane];
    float bd = (s ? dtbr : dtbf)[lane];
    float* dto = s ? dtr : dtf;
    #pragma unroll
    for (int i = 0; i < 16; ++i){
      int srcl = (i >> 2) * 16;
      float d0 = __shfl(acc[2][i & 3], srcl + 0, 64);
      float d1 = __shfl(acc[2][i & 3], srcl + 1, 64);
      float d2 = __shfl(acc[2][i & 3], srcl + 2, 64);
      float d3 = __shfl(acc[2][i & 3], srcl + 3, 64);
      float dtv = wd.x*d0 + wd.y*d1 + wd.z*d2 + wd.w*d3 + bd;
      dtv = dtv > 20.f ? dtv : log1pf(__expf(dtv));
      dto[(base + l0 + wv*16 + i)*64 + lane] = dtv;
    }
  }
}

// ================================================================ K4a: chunk compose
__global__ __launch_bounds__(256) void k4a_scanA(
    const float* __restrict__ dtf, const float* __restrict__ dtr,
    const float* __restrict__ uf,  const float* __restrict__ ur,
    const float* __restrict__ Bf,  const float* __restrict__ Br,
    const float* __restrict__ Alf, const float* __restrict__ Alr,
    float* __restrict__ P, float* __restrict__ S)
{
  int g = blockIdx.x*256 + threadIdx.x;     // 131072 threads
  int d = g & 63, c = (g >> 6) & (NCH-1), dir = (g >> 14) & 1, b = g >> 15;
  const float* dt = dir ? dtr : dtf;
  const float* u  = dir ? ur  : uf;
  const float* Bm = dir ? Br  : Bf;
  const float* Al = dir ? Alr : Alf;
  float A[16], Pp[16], Ss[16];
  #pragma unroll
  for (int n = 0; n < 16; n++){ A[n] = -__expf(Al[d*16+n]); Pp[n] = 1.f; Ss[n] = 0.f; }
  size_t base = (size_t)b*SEQL;
  for (int i = 0; i < CHL; i++){
    int s = c*CHL + i;
    int l = dir ? (SEQL-1-s) : s;
    size_t off = (base + l)*64 + d;
    float dtv = dt[off];
    float du  = dtv * u[off];
    const float4* B4 = (const float4*)(Bm + (base + l)*16);
    float4 b0 = B4[0], b1 = B4[1], b2 = B4[2], b3 = B4[3];
    float bb[16] = {b0.x,b0.y,b0.z,b0.w, b1.x,b1.y,b1.z,b1.w,
                    b2.x,b2.y,b2.z,b2.w, b3.x,b3.y,b3.z,b3.w};
    #pragma unroll
    for (int n = 0; n < 16; n++){
      float a = __expf(dtv*A[n]);
      Pp[n] *= a;
      Ss[n] = fmaf(a, Ss[n], du*bb[n]);
    }
  }
  float4* P4 = (float4*)P; float4* S4 = (float4*)S;
  #pragma unroll
  for (int k = 0; k < 4; k++){
    P4[(size_t)g*4+k] = make_float4(Pp[4*k], Pp[4*k+1], Pp[4*k+2], Pp[4*k+3]);
    S4[(size_t)g*4+k] = make_float4(Ss[4*k], Ss[4*k+1], Ss[4*k+2], Ss[4*k+3]);
  }
}

// ================================================================ K4b: carry scan
__global__ __launch_bounds__(256) void k4b_carry(float* __restrict__ P,
                                                 const float* __restrict__ S)
{
  int g = blockIdx.x*256 + threadIdx.x;     // 8192 threads
  int n = g & 15, d = (g >> 4) & 63, bd = g >> 10;
  float H = 0.f;
  for (int c = 0; c < NCH; c++){
    size_t idx = (((size_t)bd*NCH + c)*64 + d)*16 + n;
    float p = P[idx], s = S[idx];
    P[idx] = H;
    H = fmaf(p, H, s);
  }
}

// ================================================================ K4c: scan pass B
__global__ __launch_bounds__(256) void k4c_scanB(
    const float* __restrict__ dtf, const float* __restrict__ dtr,
    const float* __restrict__ uf,  const float* __restrict__ ur,
    const float* __restrict__ Bf,  const float* __restrict__ Br,
    const float* __restrict__ Cf,  const float* __restrict__ Cr,
    const float* __restrict__ Alf, const float* __restrict__ Alr,
    const float* __restrict__ Dvf, const float* __restrict__ Dvr,
    const float* __restrict__ Hpre, float* __restrict__ yf, float* __restrict__ yr)
{
  int g = blockIdx.x*256 + threadIdx.x;
  int d = g & 63, c = (g >> 6) & (NCH-1), dir = (g >> 14) & 1, b = g >> 15;
  const float* dt = dir ? dtr : dtf;
  const float* u  = dir ? ur  : uf;
  const float* Bm = dir ? Br  : Bf;
  const float* Cm = dir ? Cr  : Cf;
  const float* Al = dir ? Alr : Alf;
  float Dd = (dir ? Dvr : Dvf)[d];
  float* y = dir ? yr : yf;
  float A[16], h[16];
  const float4* H4 = (const float4*)Hpre;
  #pragma unroll
  for (int k = 0; k < 4; k++){
    float4 hv = H4[(size_t)g*4+k];
    h[4*k] = hv.x; h[4*k+1] = hv.y; h[4*k+2] = hv.z; h[4*k+3] = hv.w;
  }
  #pragma unroll
  for (int n = 0; n < 16; n++) A[n] = -__expf(Al[d*16+n]);
  size_t base = (size_t)b*SEQL;
  for (int i = 0; i < CHL; i++){
    int s = c*CHL + i;
    int l = dir ? (SEQL-1-s) : s;
    size_t off = (base + l)*64 + d;
    float dtv = dt[off];
    float uv  = u[off];
    float du  = dtv*uv;
    const float4* B4 = (const float4*)(Bm + (base + l)*16);
    const float4* C4 = (const float4*)(Cm + (base + l)*16);
    float4 b0 = B4[0], b1 = B4[1], b2 = B4[2], b3 = B4[3];
    float4 c0 = C4[0], c1 = C4[1], c2 = C4[2], c3 = C4[3];
    float bb[16] = {b0.x,b0.y,b0.z,b0.w, b1.x,b1.y,b1.z,b1.w,
                    b2.x,b2.y,b2.z,b2.w, b3.x,b3.y,b3.z,b3.w};
    float cc[16] = {c0.x,c0.y,c0.z,c0.w, c1.x,c1.y,c1.z,c1.w,
                    c2.x,c2.y,c2.z,c2.w, c3.x,c3.y,c3.z,c3.w};
    float yv = uv*Dd;
    #pragma unroll
    for (int n = 0; n < 16; n++){
      float a = __expf(dtv*A[n]);
      h[n] = fmaf(a, h[n], du*bb[n]);
      yv = fmaf(h[n], cc[n], yv);
    }
    y[off] = yv;
  }
}

// ================================================================ G3: epilogue
// phaseA: vy + RMS-norm -> bf16 A-LDS; phaseB: GEMM @ opw^T; phaseC: post-LN+gate.
__global__ __launch_bounds__(256) void g3_post(
    const float* __restrict__ yf, const float* __restrict__ yr,
    const unsigned short* __restrict__ zb, const unsigned short* __restrict__ zeb,
    const float* __restrict__ wg, const float* __restrict__ x0n,
    const float* __restrict__ in0,
    const float* __restrict__ mnw, const float* __restrict__ opw,
    const float* __restrict__ pnw, const float* __restrict__ pnb,
    float* __restrict__ out)
{
  __shared__ __align__(16) short Wl[64*72];
  __shared__ __align__(16) short Al[64*72];
  __shared__ float Dbuf[64*66];
  int tid = threadIdx.x;
  int t0 = blockIdx.x * 64;
  for (int sseg = tid; sseg < 64*8; sseg += 256){
    int row = sseg >> 3, sg = sseg & 7;
    const float* src = opw + (size_t)row*64 + sg*8;
    float4 f0 = ((const float4*)src)[0];
    float4 f1 = ((const float4*)src)[1];
    short8 v;
    v[0]=(short)f2b(f0.x); v[1]=(short)f2b(f0.y); v[2]=(short)f2b(f0.z); v[3]=(short)f2b(f0.w);
    v[4]=(short)f2b(f1.x); v[5]=(short)f2b(f1.y); v[6]=(short)f2b(f1.z); v[7]=(short)f2b(f1.w);
    *(short8*)&Wl[row*72 + sg*8] = v;
  }
  // phase A: 4 threads per token, 16 feats each
  {
    int tl = tid >> 2, p = tid & 3;
    size_t g = (size_t)(t0 + tl)*64 + p*16;
    float4 yf4[4], yr4[4];
    #pragma unroll
    for (int i = 0; i < 4; i++){
      yf4[i] = ((const float4*)(yf + g))[i];
      yr4[i] = ((const float4*)(yr + g))[i];
    }
    short8 z8a  = *(const short8*)(zb + g);
    short8 z8b  = *(const short8*)(zb + g + 8);
    short8 ze8a = *(const short8*)(zeb + g);
    short8 ze8b = *(const short8*)(zeb + g + 8);
    float vy[16]; float ss = 0.f;
    #pragma unroll
    for (int i = 0; i < 16; i++){
      float yfv = ((const float*)yf4)[i];
      float yrv = ((const float*)yr4)[i];
      float zv  = b2f((unsigned short)(i < 8 ? z8a[i] : z8b[i-8]));
      float zev = b2f((unsigned short)(i < 8 ? ze8a[i] : ze8b[i-8]));
      float v = 0.5f*(yfv*siluf(zv) + yrv*siluf(zev));
      vy[i] = v; ss += v*v;
    }
    ss += __shfl_xor(ss, 1, 64);
    ss += __shfl_xor(ss, 2, 64);
    float rms = rsqrtf(ss*(1.f/64.f) + 1e-5f);
    #pragma unroll
    for (int i = 0; i < 16; i++){
      float w = mnw[p*16 + i];
      Al[tl*72 + p*16 + i] = (short)f2b(vy[i]*rms*w);
    }
  }
  __syncthreads();
  int lane = tid & 63, wv = tid >> 6;
  int n = lane & 15, q = lane >> 4;
  {
    short8 a0 = *(const short8*)&Al[(wv*16 + n)*72 + q*8];
    short8 a1 = *(const short8*)&Al[(wv*16 + n)*72 + 32 + q*8];
    #pragma unroll
    for (int o = 0; o < 4; ++o){
      short8 b0 = *(const short8*)&Wl[(o*16 + n)*72 + q*8];
      short8 b1 = *(const short8*)&Wl[(o*16 + n)*72 + 32 + q*8];
      f32x4 c = {0.f, 0.f, 0.f, 0.f};
      c = __builtin_amdgcn_mfma_f32_16x16x32_bf16(a0, b0, c, 0, 0, 0);
      c = __builtin_amdgcn_mfma_f32_16x16x32_bf16(a1, b1, c, 0, 0, 0);
      #pragma unroll
      for (int r = 0; r < 4; ++r)
        Dbuf[(wv*16 + q*4 + r)*66 + o*16 + n] = c[r];
    }
  }
  __syncthreads();
  float gpw = pnw[lane], gpb = pnb[lane];
  for (int i = 0; i < 16; ++i){
    int tl = wv*16 + i;
    size_t off = (size_t)(t0 + tl)*64 + lane;
    float v = Dbuf[tl*66 + lane];
    float m = wsum64(v)*(1.f/64.f);
    float qv = wsum64(v*v)*(1.f/64.f) - m*m;
    float o = (v-m)*rsqrtf(qv+1e-5f)*gpw + gpb;
    o = nan2num(o, 0.f, 1.f, -1.f);
    float w = wg[off];
    float skip = nan2num(in0[off], 0.f, 1.f, -1.f);
    out[off] = fmaf(o, w, fmaf(x0n[off], 1.f - w, skip));
  }
}

// ================================================================ launcher
extern "C" void kernel_launch(void* const* d_in, const int* in_sizes, int n_in,
                              void* d_out, int out_size, void* d_ws, size_t ws_size,
                              hipStream_t stream)
{
  (void)in_sizes; (void)n_in; (void)out_size; (void)ws_size;
  const float* in0  = (const float*)d_in[0];
  const float* in1  = (const float*)d_in[1];
  const float* n0w  = (const float*)d_in[2];
  const float* n0b  = (const float*)d_in[3];
  const float* n1w  = (const float*)d_in[4];
  const float* n1b  = (const float*)d_in[5];
  const float* cww  = (const float*)d_in[6];
  const float* cwb  = (const float*)d_in[7];
  const float* cwnw = (const float*)d_in[8];
  const float* cwnb = (const float*)d_in[9];
  const float* ipw  = (const float*)d_in[10];
  const float* ipew = (const float*)d_in[11];
  const float* cwf  = (const float*)d_in[12];
  const float* cbf  = (const float*)d_in[13];
  const float* xpwf = (const float*)d_in[14];
  const float* dtwf = (const float*)d_in[15];
  const float* dtbf = (const float*)d_in[16];
  const float* Alf  = (const float*)d_in[17];
  const float* Dvf  = (const float*)d_in[18];
  const float* cwr  = (const float*)d_in[19];
  const float* cbr  = (const float*)d_in[20];
  const float* xpwr = (const float*)d_in[21];
  const float* dtwr = (const float*)d_in[22];
  const float* dtbr = (const float*)d_in[23];
  const float* Alr  = (const float*)d_in[24];
  const float* Dvr  = (const float*)d_in[25];
  const float* mnw  = (const float*)d_in[26];
  const float* opw  = (const float*)d_in[27];
  const float* pnw  = (const float*)d_in[28];
  const float* pnb  = (const float*)d_in[29];

  float* ws  = (float*)d_ws;
  float* x0n = ws + 0*EL;
  float* xa  = ws + 1*EL;   // conv input fwd; later reused as yf
  float* xe  = ws + 2*EL;   // conv input rev; later reused as yr
  float* uf  = ws + 3*EL;   // aliases w0acc (dead after k_wln)
  float* ur  = ws + 4*EL;   // aliases w1acc
  float* wg  = ws + 5*EL;
  float* dtf = ws + 6*EL;
  float* dtr = ws + 7*EL;
  float* Bf  = ws + 8*EL;              // TOK*16 each
  float* Cf  = Bf + (size_t)TOK*16;
  float* Br  = Cf + (size_t)TOK*16;
  float* Cr  = Br + (size_t)TOK*16;
  float* P   = ws + 9*EL;              // EL/2
  float* S   = P + 2*(size_t)TOK*16;   // EL/2
  unsigned short* x0b = (unsigned short*)(ws + 10*EL);
  unsigned short* x1b = x0b + EL;
  unsigned short* zb  = (unsigned short*)(ws + 11*EL);
  unsigned short* zeb = zb + EL;
  float* w0acc = uf;
  float* w1acc = ur;
  float* yfp = xa;
  float* yrp = xe;

  p1_ln<<<1024, 256, 0, stream>>>(in0, in1, n0w, n0b, n1w, n1b, x0n, x0b, x1b);
  g1_proj<<<1024, 256, 0, stream>>>(x0b, cww,      ipw,  w0acc, xa, zb);
  g1_proj<<<1024, 256, 0, stream>>>(x1b, cww + 64, ipew, w1acc, xe, zeb);
  k_wln<<<1024, 256, 0, stream>>>(w0acc, w1acc, cwb, cwnw, cwnb, wg);
  g2_convproj<<<1024, 256, 0, stream>>>(xa, xe, cwf, cbf, cwr, cbr,
                                        xpwf, xpwr, dtwf, dtbf, dtwr, dtbr,
                                        uf, ur, dtf, dtr, Bf, Cf, Br, Cr);
  k4a_scanA<<<512, 256, 0, stream>>>(dtf, dtr, uf, ur, Bf, Br, Alf, Alr, P, S);
  k4b_carry<<<32, 256, 0, stream>>>(P, S);
  k4c_scanB<<<512, 256, 0, stream>>>(dtf, dtr, uf, ur, Bf, Br, Cf, Cr,
                                     Alf, Alr, Dvf, Dvr, P, yfp, yrp);
  g3_post<<<1024, 256, 0, stream>>>(yfp, yrp, zb, zeb, wg, x0n, in0,
                                    mnw, opw, pnw, pnb, (float*)d_out);
}

// Round 3
// 378.228 us; speedup vs baseline: 1.8458x; 1.1265x over previous
//
#include <hip/hip_runtime.h>
#include <stdint.h>

#define BATCH 4
#define SEQL  16384
#define DIM   64
#define NST   16
#define TOK   (BATCH*SEQL)        /* 65536 tokens */
#define EL    ((size_t)TOK*DIM)   /* 4194304 elems per [B,L,D] array */
#define NCH   256                 /* chunks per (b,dir) */
#define CHL   64                  /* chunk length; NCH*CHL == SEQL */

typedef __attribute__((ext_vector_type(8))) short short8;
typedef __attribute__((ext_vector_type(4))) float f32x4;

__device__ __forceinline__ float nan2num(float x, float nv, float pv, float mv){
  if (__builtin_isnan(x)) return nv;
  if (__builtin_isinf(x)) return x > 0.f ? pv : mv;
  return x;
}
__device__ __forceinline__ float siluf(float x){ return x / (1.f + __expf(-x)); }
__device__ __forceinline__ float b2f(unsigned short s){
  union { unsigned u; float f; } v; v.u = ((unsigned)s) << 16; return v.f;
}
__device__ __forceinline__ unsigned short f2b(float f){
  union { float f; unsigned u; } v; v.f = f;
  unsigned r = v.u + 0x7fffu + ((v.u >> 16) & 1u);   // RNE
  return (unsigned short)(r >> 16);
}

// ================================================================ MEGA1
// 512 blocks x 128 tokens. Per stream s: stage W_s (192x64 bf16), LN(in_s)
// -> bf16 A-tile in LDS + (s==0) x0n write, GEMM -> {w partial (regs),
// conv input fp32, z bf16}. Then gate-LN from held w partials.
__global__ __launch_bounds__(256) void mega1(
    const float* __restrict__ in0, const float* __restrict__ in1,
    const float* __restrict__ n0w, const float* __restrict__ n0b,
    const float* __restrict__ n1w, const float* __restrict__ n1b,
    const float* __restrict__ cww, const float* __restrict__ cwb,
    const float* __restrict__ cwnw, const float* __restrict__ cwnb,
    const float* __restrict__ ipw, const float* __restrict__ ipew,
    float* __restrict__ x0n, float* __restrict__ wg,
    float* __restrict__ xa,  float* __restrict__ xe,
    unsigned short* __restrict__ zb, unsigned short* __restrict__ zeb)
{
  __shared__ __align__(16) short Wl[192*72];
  __shared__ __align__(16) short Al[128*72];
  int tid = threadIdx.x;
  int t0 = blockIdx.x * 128;
  int lane = tid & 63, wv = tid >> 6;
  int n = lane & 15, q = lane >> 4;
  f32x4 wacc[2][4];

  #pragma unroll
  for (int s = 0; s < 2; ++s){
    // ---- stage W_s: rows 0-63 = cww[:, s*64: s*64+64]; rows 64-191 = ip(e)w
    const float* ips = s ? ipew : ipw;
    for (int sseg = tid; sseg < 192*8; sseg += 256){
      int row = sseg >> 3, sg = sseg & 7;
      const float* src = (row < 64) ? (cww + (size_t)row*128 + s*64 + sg*8)
                                    : (ips + (size_t)(row-64)*64 + sg*8);
      float4 f0 = ((const float4*)src)[0];
      float4 f1 = ((const float4*)src)[1];
      short8 v;
      v[0]=(short)f2b(f0.x); v[1]=(short)f2b(f0.y); v[2]=(short)f2b(f0.z); v[3]=(short)f2b(f0.w);
      v[4]=(short)f2b(f1.x); v[5]=(short)f2b(f1.y); v[6]=(short)f2b(f1.z); v[7]=(short)f2b(f1.w);
      *(short8*)&Wl[row*72 + sg*8] = v;
    }
    // ---- LN + A stage (4 threads/token, 2 subpasses of 64 tokens)
    {
      const float* inp = s ? in1 : in0;
      const float* nw  = s ? n1w : n0w;
      const float* nb  = s ? n1b : n0b;
      int tl = tid >> 2, p = tid & 3;
      float gw[16], gb[16];
      #pragma unroll
      for (int i = 0; i < 4; ++i){
        float4 w4 = ((const float4*)(nw + p*16))[i];
        float4 b4 = ((const float4*)(nb + p*16))[i];
        gw[4*i]=w4.x; gw[4*i+1]=w4.y; gw[4*i+2]=w4.z; gw[4*i+3]=w4.w;
        gb[4*i]=b4.x; gb[4*i+1]=b4.y; gb[4*i+2]=b4.z; gb[4*i+3]=b4.w;
      }
      #pragma unroll
      for (int sp = 0; sp < 2; ++sp){
        int tok_l = sp*64 + tl;
        size_t ga = ((size_t)(t0 + tok_l))*64 + p*16;
        float v[16]; float s1 = 0.f, s2 = 0.f;
        #pragma unroll
        for (int i = 0; i < 4; ++i){
          float4 f = ((const float4*)(inp + ga))[i];
          float a0 = nan2num(f.x,0.f,1.f,-1.f), a1 = nan2num(f.y,0.f,1.f,-1.f);
          float a2 = nan2num(f.z,0.f,1.f,-1.f), a3 = nan2num(f.w,0.f,1.f,-1.f);
          v[4*i]=a0; v[4*i+1]=a1; v[4*i+2]=a2; v[4*i+3]=a3;
          s1 += a0+a1+a2+a3; s2 += a0*a0+a1*a1+a2*a2+a3*a3;
        }
        s1 += __shfl_xor(s1,1,64); s1 += __shfl_xor(s1,2,64);
        s2 += __shfl_xor(s2,1,64); s2 += __shfl_xor(s2,2,64);
        float m = s1*(1.f/64.f);
        float var = s2*(1.f/64.f) - m*m;
        float rs = rsqrtf(var + 1e-5f);
        float xr[16];
        #pragma unroll
        for (int i = 0; i < 16; ++i){
          float x = nan2num((v[i]-m)*rs*gw[i] + gb[i], 0.f, 1.f, -1.f);
          xr[i] = x;
          Al[tok_l*72 + p*16 + i] = (short)f2b(x);
        }
        if (s == 0){
          #pragma unroll
          for (int i = 0; i < 4; ++i)
            ((float4*)(x0n + ga))[i] = make_float4(xr[4*i],xr[4*i+1],xr[4*i+2],xr[4*i+3]);
        }
      }
    }
    __syncthreads();
    // ---- GEMM: wave handles m-tiles wv*2, wv*2+1; o-tiles 0..11
    float* outx = s ? xe : xa;
    unsigned short* outz = s ? zeb : zb;
    #pragma unroll
    for (int mi = 0; mi < 2; ++mi){
      int mt = wv*2 + mi;
      short8 a0 = *(const short8*)&Al[(mt*16 + n)*72 + q*8];
      short8 a1 = *(const short8*)&Al[(mt*16 + n)*72 + 32 + q*8];
      #pragma unroll
      for (int o = 0; o < 12; ++o){
        short8 b0 = *(const short8*)&Wl[(o*16 + n)*72 + q*8];
        short8 b1 = *(const short8*)&Wl[(o*16 + n)*72 + 32 + q*8];
        f32x4 c = {0.f, 0.f, 0.f, 0.f};
        c = __builtin_amdgcn_mfma_f32_16x16x32_bf16(a0, b0, c, 0, 0, 0);
        c = __builtin_amdgcn_mfma_f32_16x16x32_bf16(a1, b1, c, 0, 0, 0);
        if (o < 4){
          if (s == 0) wacc[mi][o] = c; else wacc[mi][o] += c;
        } else if (o < 8){
          #pragma unroll
          for (int r = 0; r < 4; ++r)
            outx[((size_t)(t0 + mt*16 + q*4 + r))*64 + (o-4)*16 + n] = c[r];
        } else {
          #pragma unroll
          for (int r = 0; r < 4; ++r)
            outz[((size_t)(t0 + mt*16 + q*4 + r))*64 + (o-8)*16 + n] = f2b(c[r]);
        }
      }
    }
    if (s == 0) __syncthreads();   // protect Wl/Al before restage
  }
  // ---- gate LN from held w partials
  float cb_l[4], gnw[4], gnb[4];
  #pragma unroll
  for (int o = 0; o < 4; ++o){
    cb_l[o] = cwb[o*16+n]; gnw[o] = cwnw[o*16+n]; gnb[o] = cwnb[o*16+n];
  }
  #pragma unroll
  for (int mi = 0; mi < 2; ++mi){
    #pragma unroll
    for (int r = 0; r < 4; ++r){
      float v[4]; float sv = 0.f, sq = 0.f;
      #pragma unroll
      for (int o = 0; o < 4; ++o){
        v[o] = wacc[mi][o][r] + cb_l[o];
        sv += v[o]; sq += v[o]*v[o];
      }
      sv += __shfl_xor(sv,1,64); sv += __shfl_xor(sv,2,64);
      sv += __shfl_xor(sv,4,64); sv += __shfl_xor(sv,8,64);
      sq += __shfl_xor(sq,1,64); sq += __shfl_xor(sq,2,64);
      sq += __shfl_xor(sq,4,64); sq += __shfl_xor(sq,8,64);
      float m = sv*(1.f/64.f);
      float var = sq*(1.f/64.f) - m*m;
      float rs = rsqrtf(var + 1e-5f);
      size_t tok = (size_t)t0 + (wv*2+mi)*16 + q*4 + r;
      #pragma unroll
      for (int o = 0; o < 4; ++o){
        float wn = (v[o]-m)*rs*gnw[o] + gnb[o];
        wn = nan2num(wn, 0.5f, 1.f, 0.f);
        wn = 1.f/(1.f + __expf(-wn));
        wn = fminf(fmaxf(wn, 0.01f), 0.99f);
        wg[tok*64 + o*16 + n] = wn;
      }
    }
  }
}

// ================================================================ G2: conv + xproj
// 512 blocks x 128 tokens. Thread = (d, 4 consecutive l): register-reused taps.
// GEMM [128x64]@[64x48] per stream -> B, C, dlt[T,4] (rank-4 dt, recomputed later).
__global__ __launch_bounds__(256) void g2_convproj(
    const float* __restrict__ xa, const float* __restrict__ xe,
    const float* __restrict__ cwf, const float* __restrict__ cbf,
    const float* __restrict__ cwr, const float* __restrict__ cbr,
    const float* __restrict__ xpwf, const float* __restrict__ xpwr,
    float* __restrict__ uf, float* __restrict__ ur,
    float* __restrict__ dltf, float* __restrict__ dltr,
    float* __restrict__ Bf, float* __restrict__ Cf,
    float* __restrict__ Br, float* __restrict__ Cr)
{
  __shared__ __align__(16) short Wl[2*48*72];
  __shared__ __align__(16) short Al[2*128*72];
  int tid = threadIdx.x;
  int b = blockIdx.x >> 7, l0 = (blockIdx.x & 127) * 128;
  size_t base = (size_t)b * SEQL;
  // stage W: rows 0-15 = B (xp rows 4-19), 16-31 = C (20-35), 32-35 = dt (0-3)
  for (int sseg = tid; sseg < 2*48*8; sseg += 256){
    int s = sseg >= 48*8;
    int rs = sseg - s*48*8;
    int row = rs >> 3, sg = rs & 7;
    const float* xp = s ? xpwr : xpwf;
    short8 v = {0,0,0,0,0,0,0,0};
    int srcrow = (row < 32) ? (4+row) : (row < 36) ? (row-32) : -1;
    if (srcrow >= 0){
      const float* src = xp + (size_t)srcrow*64 + sg*8;
      float4 f0 = ((const float4*)src)[0];
      float4 f1 = ((const float4*)src)[1];
      v[0]=(short)f2b(f0.x); v[1]=(short)f2b(f0.y); v[2]=(short)f2b(f0.z); v[3]=(short)f2b(f0.w);
      v[4]=(short)f2b(f1.x); v[5]=(short)f2b(f1.y); v[6]=(short)f2b(f1.z); v[7]=(short)f2b(f1.w);
    }
    *(short8*)&Wl[(s*48+row)*72 + sg*8] = v;
  }
  // conv + silu + stage A + write u
  {
    int d = tid & 63, lq = tid >> 6;
    float4 wf4 = ((const float4*)cwf)[d];
    float4 wr4 = ((const float4*)cwr)[d];
    float bf = cbf[d], brr = cbr[d];
    for (int i = 0; i < 8; ++i){
      int ll = i*16 + lq*4;
      int gl = l0 + ll;
      float rv[7], sv[7];
      #pragma unroll
      for (int j = 0; j < 7; ++j){
        int li = gl - 3 + j;
        rv[j] = (li >= 0) ? xa[(base + li)*64 + d] : 0.f;
        int lj = gl + j;
        sv[j] = (lj < SEQL) ? xe[(base + lj)*64 + d] : 0.f;
      }
      #pragma unroll
      for (int k = 0; k < 4; ++k){
        float a = bf + wf4.x*rv[k] + wf4.y*rv[k+1] + wf4.z*rv[k+2] + wf4.w*rv[k+3];
        a = siluf(a);
        uf[(base + gl + k)*64 + d] = a;
        Al[(ll+k)*72 + d] = (short)f2b(a);
        float r = brr + wr4.w*sv[k] + wr4.z*sv[k+1] + wr4.y*sv[k+2] + wr4.x*sv[k+3];
        r = siluf(r);
        ur[(base + gl + k)*64 + d] = r;
        Al[(128 + ll + k)*72 + d] = (short)f2b(r);
      }
    }
  }
  __syncthreads();
  int lane = tid & 63, wv = tid >> 6;
  int n = lane & 15, q = lane >> 4;
  #pragma unroll
  for (int s = 0; s < 2; ++s){
    const short* As = &Al[s*128*72];
    const short* Ws = &Wl[s*48*72];
    float* Bo = s ? Br : Bf;
    float* Co = s ? Cr : Cf;
    float* Do = s ? dltr : dltf;
    #pragma unroll
    for (int mi = 0; mi < 2; ++mi){
      int mt = wv*2 + mi;
      short8 a0 = *(const short8*)&As[(mt*16 + n)*72 + q*8];
      short8 a1 = *(const short8*)&As[(mt*16 + n)*72 + 32 + q*8];
      f32x4 acc[3];
      #pragma unroll
      for (int o = 0; o < 3; ++o){
        short8 b0 = *(const short8*)&Ws[(o*16 + n)*72 + q*8];
        short8 b1 = *(const short8*)&Ws[(o*16 + n)*72 + 32 + q*8];
        f32x4 c = {0.f, 0.f, 0.f, 0.f};
        c = __builtin_amdgcn_mfma_f32_16x16x32_bf16(a0, b0, c, 0, 0, 0);
        c = __builtin_amdgcn_mfma_f32_16x16x32_bf16(a1, b1, c, 0, 0, 0);
        acc[o] = c;
      }
      #pragma unroll
      for (int r = 0; r < 4; ++r){
        size_t tok = base + l0 + mt*16 + q*4 + r;
        Bo[tok*16 + n] = acc[0][r];
        Co[tok*16 + n] = acc[1][r];
        if (n < 4) Do[tok*4 + n] = acc[2][r];
      }
    }
  }
}

__device__ __forceinline__ float dt_from_dlt(const float* __restrict__ dlt,
                                             size_t tok, float4 wd, float bd){
  float4 dl = *(const float4*)(dlt + tok*4);
  float dtv = wd.x*dl.x + wd.y*dl.y + wd.z*dl.z + wd.w*dl.w + bd;
  return dtv > 20.f ? dtv : log1pf(__expf(dtv));
}

// ================================================================ K4a: chunk compose
__global__ __launch_bounds__(256) void k4a_scanA(
    const float* __restrict__ dltf, const float* __restrict__ dltr,
    const float* __restrict__ dtwf, const float* __restrict__ dtbf,
    const float* __restrict__ dtwr, const float* __restrict__ dtbr,
    const float* __restrict__ uf,  const float* __restrict__ ur,
    const float* __restrict__ Bf,  const float* __restrict__ Br,
    const float* __restrict__ Alf, const float* __restrict__ Alr,
    float* __restrict__ P, float* __restrict__ S)
{
  int g = blockIdx.x*256 + threadIdx.x;     // 131072 threads
  int d = g & 63, c = (g >> 6) & (NCH-1), dir = (g >> 14) & 1, b = g >> 15;
  const float* dlt = dir ? dltr : dltf;
  const float* u  = dir ? ur  : uf;
  const float* Bm = dir ? Br  : Bf;
  const float* Al = dir ? Alr : Alf;
  float4 wd = ((const float4*)(dir ? dtwr : dtwf))[d];
  float bd = (dir ? dtbr : dtbf)[d];
  float A[16], Pp[16], Ss[16];
  #pragma unroll
  for (int n = 0; n < 16; n++){ A[n] = -__expf(Al[d*16+n]); Pp[n] = 1.f; Ss[n] = 0.f; }
  size_t base = (size_t)b*SEQL;
  for (int i = 0; i < CHL; i++){
    int s = c*CHL + i;
    int l = dir ? (SEQL-1-s) : s;
    size_t tok = base + l;
    float dtv = dt_from_dlt(dlt, tok, wd, bd);
    float du  = dtv * u[tok*64 + d];
    const float4* B4 = (const float4*)(Bm + tok*16);
    float4 b0 = B4[0], b1 = B4[1], b2 = B4[2], b3 = B4[3];
    float bb[16] = {b0.x,b0.y,b0.z,b0.w, b1.x,b1.y,b1.z,b1.w,
                    b2.x,b2.y,b2.z,b2.w, b3.x,b3.y,b3.z,b3.w};
    #pragma unroll
    for (int n = 0; n < 16; n++){
      float a = __expf(dtv*A[n]);
      Pp[n] *= a;
      Ss[n] = fmaf(a, Ss[n], du*bb[n]);
    }
  }
  float4* P4 = (float4*)P; float4* S4 = (float4*)S;
  #pragma unroll
  for (int k = 0; k < 4; k++){
    P4[(size_t)g*4+k] = make_float4(Pp[4*k], Pp[4*k+1], Pp[4*k+2], Pp[4*k+3]);
    S4[(size_t)g*4+k] = make_float4(Ss[4*k], Ss[4*k+1], Ss[4*k+2], Ss[4*k+3]);
  }
}

// ================================================================ K4b: Kogge-Stone carry scan
// block per (b,dir,d) = 512 blocks; thread c in [0,256) holds 16 (p,s) pairs.
__global__ __launch_bounds__(256) void k4b_ks(float* __restrict__ P,
                                              const float* __restrict__ S)
{
  __shared__ float Pl[256*18], Sl[256*18];
  int c = threadIdx.x;
  int d = blockIdx.x & 63, bd = blockIdx.x >> 6;
  size_t idx = (((size_t)bd*NCH + c)*64 + d)*16;
  float p[16], s[16];
  #pragma unroll
  for (int k = 0; k < 4; k++){
    float4 pv = ((const float4*)(P + idx))[k];
    float4 sv = ((const float4*)(S + idx))[k];
    p[4*k]=pv.x; p[4*k+1]=pv.y; p[4*k+2]=pv.z; p[4*k+3]=pv.w;
    s[4*k]=sv.x; s[4*k+1]=sv.y; s[4*k+2]=sv.z; s[4*k+3]=sv.w;
  }
  #pragma unroll
  for (int j = 0; j < 8; j++){
    *(float2*)&Pl[c*18 + 2*j] = make_float2(p[2*j], p[2*j+1]);
    *(float2*)&Sl[c*18 + 2*j] = make_float2(s[2*j], s[2*j+1]);
  }
  for (int step = 1; step < NCH; step <<= 1){
    __syncthreads();
    float pp[16], ss[16];
    bool act = (c >= step);
    if (act){
      #pragma unroll
      for (int j = 0; j < 8; j++){
        float2 tp = *(const float2*)&Pl[(c-step)*18 + 2*j];
        float2 ts = *(const float2*)&Sl[(c-step)*18 + 2*j];
        pp[2*j]=tp.x; pp[2*j+1]=tp.y; ss[2*j]=ts.x; ss[2*j+1]=ts.y;
      }
    }
    __syncthreads();
    if (act){
      #pragma unroll
      for (int n = 0; n < 16; n++){
        s[n] = fmaf(p[n], ss[n], s[n]);
        p[n] *= pp[n];
      }
      #pragma unroll
      for (int j = 0; j < 8; j++){
        *(float2*)&Pl[c*18 + 2*j] = make_float2(p[2*j], p[2*j+1]);
        *(float2*)&Sl[c*18 + 2*j] = make_float2(s[2*j], s[2*j+1]);
      }
    }
  }
  __syncthreads();
  float ho[16];
  if (c == 0){
    #pragma unroll
    for (int n = 0; n < 16; n++) ho[n] = 0.f;
  } else {
    #pragma unroll
    for (int j = 0; j < 8; j++){
      float2 ts = *(const float2*)&Sl[(c-1)*18 + 2*j];
      ho[2*j]=ts.x; ho[2*j+1]=ts.y;
    }
  }
  #pragma unroll
  for (int k = 0; k < 4; k++)
    ((float4*)(P + idx))[k] = make_float4(ho[4*k], ho[4*k+1], ho[4*k+2], ho[4*k+3]);
}

// ================================================================ K4c: scan pass B
__global__ __launch_bounds__(256) void k4c_scanB(
    const float* __restrict__ dltf, const float* __restrict__ dltr,
    const float* __restrict__ dtwf, const float* __restrict__ dtbf,
    const float* __restrict__ dtwr, const float* __restrict__ dtbr,
    const float* __restrict__ uf,  const float* __restrict__ ur,
    const float* __restrict__ Bf,  const float* __restrict__ Br,
    const float* __restrict__ Cf,  const float* __restrict__ Cr,
    const float* __restrict__ Alf, const float* __restrict__ Alr,
    const float* __restrict__ Dvf, const float* __restrict__ Dvr,
    const float* __restrict__ Hpre, float* __restrict__ yf, float* __restrict__ yr)
{
  int g = blockIdx.x*256 + threadIdx.x;
  int d = g & 63, c = (g >> 6) & (NCH-1), dir = (g >> 14) & 1, b = g >> 15;
  const float* dlt = dir ? dltr : dltf;
  const float* u  = dir ? ur  : uf;
  const float* Bm = dir ? Br  : Bf;
  const float* Cm = dir ? Cr  : Cf;
  const float* Al = dir ? Alr : Alf;
  float4 wd = ((const float4*)(dir ? dtwr : dtwf))[d];
  float bd = (dir ? dtbr : dtbf)[d];
  float Dd = (dir ? Dvr : Dvf)[d];
  float* y = dir ? yr : yf;
  float A[16], h[16];
  const float4* H4 = (const float4*)Hpre;
  #pragma unroll
  for (int k = 0; k < 4; k++){
    float4 hv = H4[(size_t)g*4+k];
    h[4*k] = hv.x; h[4*k+1] = hv.y; h[4*k+2] = hv.z; h[4*k+3] = hv.w;
  }
  #pragma unroll
  for (int n = 0; n < 16; n++) A[n] = -__expf(Al[d*16+n]);
  size_t base = (size_t)b*SEQL;
  for (int i = 0; i < CHL; i++){
    int s = c*CHL + i;
    int l = dir ? (SEQL-1-s) : s;
    size_t tok = base + l;
    float dtv = dt_from_dlt(dlt, tok, wd, bd);
    float uv  = u[tok*64 + d];
    float du  = dtv*uv;
    const float4* B4 = (const float4*)(Bm + tok*16);
    const float4* C4 = (const float4*)(Cm + tok*16);
    float4 b0 = B4[0], b1 = B4[1], b2 = B4[2], b3 = B4[3];
    float4 c0 = C4[0], c1 = C4[1], c2 = C4[2], c3 = C4[3];
    float bb[16] = {b0.x,b0.y,b0.z,b0.w, b1.x,b1.y,b1.z,b1.w,
                    b2.x,b2.y,b2.z,b2.w, b3.x,b3.y,b3.z,b3.w};
    float cc[16] = {c0.x,c0.y,c0.z,c0.w, c1.x,c1.y,c1.z,c1.w,
                    c2.x,c2.y,c2.z,c2.w, c3.x,c3.y,c3.z,c3.w};
    float yv = uv*Dd;
    #pragma unroll
    for (int n = 0; n < 16; n++){
      float a = __expf(dtv*A[n]);
      h[n] = fmaf(a, h[n], du*bb[n]);
      yv = fmaf(h[n], cc[n], yv);
    }
    y[tok*64 + d] = yv;
  }
}

// ================================================================ G3: epilogue
__global__ __launch_bounds__(256) void g3_post(
    const float* __restrict__ yf, const float* __restrict__ yr,
    const unsigned short* __restrict__ zb, const unsigned short* __restrict__ zeb,
    const float* __restrict__ wg, const float* __restrict__ x0n,
    const float* __restrict__ in0,
    const float* __restrict__ mnw, const float* __restrict__ opw,
    const float* __restrict__ pnw, const float* __restrict__ pnb,
    float* __restrict__ out)
{
  __shared__ __align__(16) short Wl[64*72];
  __shared__ __align__(16) short Al[64*72];
  __shared__ float Dbuf[64*66];
  int tid = threadIdx.x;
  int t0 = blockIdx.x * 64;
  for (int sseg = tid; sseg < 64*8; sseg += 256){
    int row = sseg >> 3, sg = sseg & 7;
    const float* src = opw + (size_t)row*64 + sg*8;
    float4 f0 = ((const float4*)src)[0];
    float4 f1 = ((const float4*)src)[1];
    short8 v;
    v[0]=(short)f2b(f0.x); v[1]=(short)f2b(f0.y); v[2]=(short)f2b(f0.z); v[3]=(short)f2b(f0.w);
    v[4]=(short)f2b(f1.x); v[5]=(short)f2b(f1.y); v[6]=(short)f2b(f1.z); v[7]=(short)f2b(f1.w);
    *(short8*)&Wl[row*72 + sg*8] = v;
  }
  {
    int tl = tid >> 2, p = tid & 3;
    size_t g = (size_t)(t0 + tl)*64 + p*16;
    float4 yf4[4], yr4[4];
    #pragma unroll
    for (int i = 0; i < 4; i++){
      yf4[i] = ((const float4*)(yf + g))[i];
      yr4[i] = ((const float4*)(yr + g))[i];
    }
    short8 z8a  = *(const short8*)(zb + g);
    short8 z8b  = *(const short8*)(zb + g + 8);
    short8 ze8a = *(const short8*)(zeb + g);
    short8 ze8b = *(const short8*)(zeb + g + 8);
    float vy[16]; float ss = 0.f;
    #pragma unroll
    for (int i = 0; i < 16; i++){
      float yfv = ((const float*)yf4)[i];
      float yrv = ((const float*)yr4)[i];
      float zv  = b2f((unsigned short)(i < 8 ? z8a[i] : z8b[i-8]));
      float zev = b2f((unsigned short)(i < 8 ? ze8a[i] : ze8b[i-8]));
      float v = 0.5f*(yfv*siluf(zv) + yrv*siluf(zev));
      vy[i] = v; ss += v*v;
    }
    ss += __shfl_xor(ss, 1, 64);
    ss += __shfl_xor(ss, 2, 64);
    float rms = rsqrtf(ss*(1.f/64.f) + 1e-5f);
    #pragma unroll
    for (int i = 0; i < 16; i++){
      float w = mnw[p*16 + i];
      Al[tl*72 + p*16 + i] = (short)f2b(vy[i]*rms*w);
    }
  }
  __syncthreads();
  int lane = tid & 63, wv = tid >> 6;
  int n = lane & 15, q = lane >> 4;
  {
    short8 a0 = *(const short8*)&Al[(wv*16 + n)*72 + q*8];
    short8 a1 = *(const short8*)&Al[(wv*16 + n)*72 + 32 + q*8];
    #pragma unroll
    for (int o = 0; o < 4; ++o){
      short8 b0 = *(const short8*)&Wl[(o*16 + n)*72 + q*8];
      short8 b1 = *(const short8*)&Wl[(o*16 + n)*72 + 32 + q*8];
      f32x4 c = {0.f, 0.f, 0.f, 0.f};
      c = __builtin_amdgcn_mfma_f32_16x16x32_bf16(a0, b0, c, 0, 0, 0);
      c = __builtin_amdgcn_mfma_f32_16x16x32_bf16(a1, b1, c, 0, 0, 0);
      #pragma unroll
      for (int r = 0; r < 4; ++r)
        Dbuf[(wv*16 + q*4 + r)*66 + o*16 + n] = c[r];
    }
  }
  __syncthreads();
  float gpw = pnw[lane], gpb = pnb[lane];
  float s1, s2;
  for (int i = 0; i < 16; ++i){
    int tl = wv*16 + i;
    size_t off = (size_t)(t0 + tl)*64 + lane;
    float v = Dbuf[tl*66 + lane];
    s1 = v; s2 = v*v;
    #pragma unroll
    for (int o2 = 32; o2 > 0; o2 >>= 1){ s1 += __shfl_xor(s1,o2,64); s2 += __shfl_xor(s2,o2,64); }
    float m = s1*(1.f/64.f);
    float qv = s2*(1.f/64.f) - m*m;
    float o = (v-m)*rsqrtf(qv+1e-5f)*gpw + gpb;
    o = nan2num(o, 0.f, 1.f, -1.f);
    float w = wg[off];
    float skip = nan2num(in0[off], 0.f, 1.f, -1.f);
    out[off] = fmaf(o, w, fmaf(x0n[off], 1.f - w, skip));
  }
}

// ================================================================ launcher
extern "C" void kernel_launch(void* const* d_in, const int* in_sizes, int n_in,
                              void* d_out, int out_size, void* d_ws, size_t ws_size,
                              hipStream_t stream)
{
  (void)in_sizes; (void)n_in; (void)out_size; (void)ws_size;
  const float* in0  = (const float*)d_in[0];
  const float* in1  = (const float*)d_in[1];
  const float* n0w  = (const float*)d_in[2];
  const float* n0b  = (const float*)d_in[3];
  const float* n1w  = (const float*)d_in[4];
  const float* n1b  = (const float*)d_in[5];
  const float* cww  = (const float*)d_in[6];
  const float* cwb  = (const float*)d_in[7];
  const float* cwnw = (const float*)d_in[8];
  const float* cwnb = (const float*)d_in[9];
  const float* ipw  = (const float*)d_in[10];
  const float* ipew = (const float*)d_in[11];
  const float* cwf  = (const float*)d_in[12];
  const float* cbf  = (const float*)d_in[13];
  const float* xpwf = (const float*)d_in[14];
  const float* dtwf = (const float*)d_in[15];
  const float* dtbf = (const float*)d_in[16];
  const float* Alf  = (const float*)d_in[17];
  const float* Dvf  = (const float*)d_in[18];
  const float* cwr  = (const float*)d_in[19];
  const float* cbr  = (const float*)d_in[20];
  const float* xpwr = (const float*)d_in[21];
  const float* dtwr = (const float*)d_in[22];
  const float* dtbr = (const float*)d_in[23];
  const float* Alr  = (const float*)d_in[24];
  const float* Dvr  = (const float*)d_in[25];
  const float* mnw  = (const float*)d_in[26];
  const float* opw  = (const float*)d_in[27];
  const float* pnw  = (const float*)d_in[28];
  const float* pnb  = (const float*)d_in[29];

  float* ws  = (float*)d_ws;
  float* x0n = ws + 0*EL;
  float* xa  = ws + 1*EL;   // conv input fwd; reused as yf
  float* xe  = ws + 2*EL;   // conv input rev; reused as yr
  float* uf  = ws + 3*EL;
  float* ur  = ws + 4*EL;
  float* wg  = ws + 5*EL;
  float* Bf  = ws + 6*EL;              // TOK*16 each (4 arrays = EL total)
  float* Cf  = Bf + (size_t)TOK*16;
  float* Br  = Cf + (size_t)TOK*16;
  float* Cr  = Br + (size_t)TOK*16;
  float* P   = ws + 7*EL;              // EL/2
  float* S   = P + 2*(size_t)TOK*16;   // EL/2
  unsigned short* zb  = (unsigned short*)(ws + 8*EL);
  unsigned short* zeb = zb + EL;
  float* dltf = ws + 9*EL;             // TOK*4 each
  float* dltr = dltf + (size_t)TOK*4;
  float* yfp = xa;
  float* yrp = xe;

  mega1<<<512, 256, 0, stream>>>(in0, in1, n0w, n0b, n1w, n1b, cww, cwb,
                                 cwnw, cwnb, ipw, ipew,
                                 x0n, wg, xa, xe, zb, zeb);
  g2_convproj<<<512, 256, 0, stream>>>(xa, xe, cwf, cbf, cwr, cbr,
                                       xpwf, xpwr,
                                       uf, ur, dltf, dltr, Bf, Cf, Br, Cr);
  k4a_scanA<<<512, 256, 0, stream>>>(dltf, dltr, dtwf, dtbf, dtwr, dtbr,
                                     uf, ur, Bf, Br, Alf, Alr, P, S);
  k4b_ks<<<512, 256, 0, stream>>>(P, S);
  k4c_scanB<<<512, 256, 0, stream>>>(dltf, dltr, dtwf, dtbf, dtwr, dtbr,
                                     uf, ur, Bf, Br, Cf, Cr,
                                     Alf, Alr, Dvf, Dvr, P, yfp, yrp);
  g3_post<<<1024, 256, 0, stream>>>(yfp, yrp, zb, zeb, wg, x0n, in0,
                                    mnw, opw, pnw, pnb, (float*)d_out);
}